// Round 10
// baseline (250.264 us; speedup 1.0000x reference)
//
#include <hip/hip_runtime.h>
#include <math.h>

#define N_PIX 65536
#define EPSF 1e-6f
#define CHUNKS 16
#define PX_PER_CHUNK 4096   // 65536 / 16
#define PX_PER_WAVE 1024    // 4 waves per block, 16 super-tiles of 64 px
#define N_TILES (PX_PER_WAVE / 64)
#define N_JOBS 48           // 2 imgs * 8 batch * 3 channels
#define LN2_50 34.65735903f // 50 * ln(2): log2 -> scaled-ln

typedef __attribute__((ext_vector_type(2))) float f2;
using short8 = __attribute__((ext_vector_type(8))) short;
using f32x4  = __attribute__((ext_vector_type(4))) float;

__device__ __forceinline__ float rcp_fast(float x) { return __builtin_amdgcn_rcpf(x); }

#if __has_builtin(__builtin_amdgcn_cvt_pk_bf16_f32)
typedef __attribute__((ext_vector_type(2))) __bf16 bf16x2_t;
__device__ __forceinline__ uint32_t pk_bf16(float a, float b) {
    return __builtin_bit_cast(uint32_t, __builtin_amdgcn_cvt_pk_bf16_f32(a, b));
}
#else
// fallback: round-half-up (inputs positive finite), 3 ops
__device__ __forceinline__ uint32_t pk_bf16(float a, float b) {
    const uint32_t ua = __builtin_bit_cast(uint32_t, a) + 0x8000u;
    const uint32_t ub = __builtin_bit_cast(uint32_t, b) + 0x8000u;
    return __builtin_amdgcn_perm(ub, ua, 0x07060302u);
}
#endif

// phase A: pixel -> (u*50, v*50, weight); log2-based (ln2 folded into scale)
__device__ __forceinline__ float4 phaseA(float pr, float pg, float pb, int c) {
    const float r  = pr + EPSF;
    const float g  = pg + EPSF;
    const float bl = pb + EPSF;
    const float wgt = sqrtf(fmaf(r, r, fmaf(g, g, bl * bl)));
    const float lr = __log2f(r), lg = __log2f(g), lb2 = __log2f(bl);
    // channel c: u = l_c - l_a, v = l_c - l_b;  c0:(a,b)=(g,b) c1:(r,b) c2:(r,g)
    const float l0 = (c == 0) ? lr : ((c == 1) ? lg : lb2);
    const float lu = (c == 0) ? lg : lr;
    const float lv = (c == 2) ? lg : lb2;
    return make_float4((l0 - lu) * LN2_50, (l0 - lv) * LN2_50, wgt, 0.0f);
}

// ---------------------------------------------------------------------------
// Kernel 1: per (job, chunk) partial 64x64 histogram via bf16 MFMA with
// fragment-direct operand generation. 256 thr/block x 768 blocks. R9's
// verified structure (k1 = 105us, VALUBusy 68% = the eval-work floor):
// atomic-free chunked epilogue, rolled super-tile loop, conflict-free padded
// staging (SQ_LDS_BANK_CONFLICT=0), rcp-of-4-product, HW bf16 pack.
// Block 0 also zeroes out[0] (removes the memset dispatch; kernel-boundary
// ordering makes it visible to finalize_kernel).
// ---------------------------------------------------------------------------
__global__ __launch_bounds__(256, 4) void hist_kernel(
    const float* __restrict__ x, const float* __restrict__ y,
    float* __restrict__ partial, float* __restrict__ out)
{
    const int blk = blockIdx.x;            // 0..767
    const int chunk = blk & (CHUNKS - 1);
    const int job = blk / CHUNKS;          // 0..47
    const int c = job % 3;
    const int ib = job / 3;                // img*8 + b
    const int img = ib >> 3;
    const int b = ib & 7;
    const float* __restrict__ src = (img == 0 ? x : y) + (size_t)b * 3 * N_PIX;

    if (blk == 0 && threadIdx.x == 0) out[0] = 0.0f;   // replaces memset dispatch

    __shared__ __align__(16) float lds[4096];   // 16 KB: wbufs / epilogue strips
    const int tid = threadIdx.x;
    const int lane = tid & 63;
    const int wv = tid >> 6;
    float* __restrict__ wbuf = lds + wv * 288;  // 64 px * float4, +16B pad per 8 px

    const int quad = lane >> 4;
    const int l15 = lane & 15;
    // negated scaled centers for this lane's 4 m-rows: -(c_m * 50), m = mt*16+l15
    f2 ncb01, ncb23;
    {
        const float c0 = (-3.0f + (float)(l15)      * (6.0f / 63.0f)) * 50.0f;
        const float c1 = (-3.0f + (float)(16 + l15) * (6.0f / 63.0f)) * 50.0f;
        const float c2 = (-3.0f + (float)(32 + l15) * (6.0f / 63.0f)) * 50.0f;
        const float c3 = (-3.0f + (float)(48 + l15) * (6.0f / 63.0f)) * 50.0f;
        ncb01 = (f2){-c0, -c1};
        ncb23 = (f2){-c2, -c3};
    }
    const f2 one2 = {1.0f, 1.0f};

    f32x4 acc[16];                         // acc[mt*4+nt]
#pragma unroll
    for (int i = 0; i < 16; ++i) acc[i] = (f32x4){0.f, 0.f, 0.f, 0.f};

    const int px0 = chunk * PX_PER_CHUNK + wv * PX_PER_WAVE;

    // prefetch super-tile 0
    float pr, pg, pb;
    {
        const int n = px0 + lane;
        pr = src[n]; pg = src[N_PIX + n]; pb = src[2 * N_PIX + n];
    }

#pragma unroll 1
    for (int st = 0; st < N_TILES; ++st) {
        // ---- Phase A: one pixel per lane; stage to LDS (same-wave, in-order) ----
        const float4 uvw = phaseA(pr, pg, pb, c);
        *(float4*)(wbuf + lane * 4 + (lane >> 3) * 4) = uvw;

        if (st + 1 < N_TILES) {            // prefetch next tile's raw pixels
            const int n2 = px0 + (st + 1) * 64 + lane;
            pr = src[n2]; pg = src[N_PIX + n2]; pb = src[2 * N_PIX + n2];
        }

#pragma unroll
        for (int h = 0; h < 2; ++h) {              // two K=32 halves
            const int base = h * 32 + quad * 8;    // first pixel this lane consumes
            const float4* __restrict__ pbase =
                (const float4*)(wbuf + base * 4 + (base >> 3) * 4);
            int aU[4][4], aV[4][4];                // fragment words [mt][jp]

#pragma unroll
            for (int jp = 0; jp < 4; ++jp) {       // j = 2jp (even), 2jp+1 (odd)
                const float4 pe = pbase[2 * jp];
                const float4 po = pbase[2 * jp + 1];

                float aue[4], auo[4], bve[4], bvo[4];
#pragma unroll
                for (int eo = 0; eo < 2; ++eo) {
                    const float ru = eo ? po.x : pe.x;
                    const float rv = eo ? po.y : pe.y;
                    const float rw = eo ? po.z : pe.z;
                    float* au = eo ? auo : aue;
                    float* bv = eo ? bvo : bve;

                    const f2 ruu = {ru, ru};
                    const f2 tu01 = ruu + ncb01;
                    const f2 tu23 = ruu + ncb23;
                    const f2 qu01 = __builtin_elementwise_fma(tu01, tu01, one2);
                    const f2 qu23 = __builtin_elementwise_fma(tu23, tu23, one2);
                    // one rcp serves 4 denominators (max product ~6.5e19, fp32-safe)
                    const float pu01 = qu01.x * qu01.y;
                    const float pu23 = qu23.x * qu23.y;
                    const float Ru = rcp_fast(pu01 * pu23) * rw;   // fold w
                    const float ru01 = Ru * pu23, ru23 = Ru * pu01;
                    au[0] = ru01 * qu01.y; au[1] = ru01 * qu01.x;
                    au[2] = ru23 * qu23.y; au[3] = ru23 * qu23.x;

                    const f2 rvv = {rv, rv};
                    const f2 tv01 = rvv + ncb01;
                    const f2 tv23 = rvv + ncb23;
                    const f2 qv01 = __builtin_elementwise_fma(tv01, tv01, one2);
                    const f2 qv23 = __builtin_elementwise_fma(tv23, tv23, one2);
                    const float pv01 = qv01.x * qv01.y;
                    const float pv23 = qv23.x * qv23.y;
                    const float Rv = rcp_fast(pv01 * pv23);
                    const float rv01 = Rv * pv23, rv23 = Rv * pv01;
                    bv[0] = rv01 * qv01.y; bv[1] = rv01 * qv01.x;
                    bv[2] = rv23 * qv23.y; bv[3] = rv23 * qv23.x;
                }
#pragma unroll
                for (int mt = 0; mt < 4; ++mt) {
                    aU[mt][jp] = pk_bf16(aue[mt], auo[mt]);
                    aV[mt][jp] = pk_bf16(bve[mt], bvo[mt]);
                }
            }

            short8 af[4], bf[4];
#pragma unroll
            for (int mt = 0; mt < 4; ++mt) {
                af[mt] = __builtin_bit_cast(short8,
                    make_int4(aU[mt][0], aU[mt][1], aU[mt][2], aU[mt][3]));
                bf[mt] = __builtin_bit_cast(short8,
                    make_int4(aV[mt][0], aV[mt][1], aV[mt][2], aV[mt][3]));
            }
#pragma unroll
            for (int mt = 0; mt < 4; ++mt)
#pragma unroll
                for (int nt = 0; nt < 4; ++nt)
                    acc[mt * 4 + nt] = __builtin_amdgcn_mfma_f32_16x16x32_bf16(
                        af[mt], bf[nt], acc[mt * 4 + nt], 0, 0, 0);
        }
    }

    // ---- Atomic-free epilogue: 4 chunks over mt; linear b128 traffic only ----
    float* __restrict__ outp = partial + (size_t)blk * 4096;
#pragma unroll 1
    for (int ch = 0; ch < 4; ++ch) {
        __syncthreads();                   // previous chunk (or main loop) done
#pragma unroll
        for (int nt = 0; nt < 4; ++nt)     // wave strip: [wv][nt*256 + lane*4 + i]
            *(f32x4*)(lds + wv * 1024 + nt * 256 + lane * 4) = acc[ch * 4 + nt];
        __syncthreads();
        const int e4 = tid * 4;            // 0..1023, linear -> conflict-free b128
        const f32x4 s0 = *(const f32x4*)(lds +        e4);
        const f32x4 s1 = *(const f32x4*)(lds + 1024 + e4);
        const f32x4 s2 = *(const f32x4*)(lds + 2048 + e4);
        const f32x4 s3 = *(const f32x4*)(lds + 3072 + e4);
        const f32x4 s = (s0 + s1) + (s2 + s3);
        // e4 = nt*256 + l*4;  m = ch*16 + (l>>4)*4 + i;  n = nt*16 + (l&15)
        const int l = tid & 63;
        const int n = ((tid >> 6) << 4) | (l & 15);
        float* op = outp + (ch * 16 + (l >> 4) * 4) * 64 + n;
        op[0] = s.x; op[64] = s.y; op[128] = s.z; op[192] = s.w;
    }
}

// ---------------------------------------------------------------------------
// Kernel 2: fused finalize — one block per batch (8 x 1024). Each thread owns
// 12 of the 12288 (channel, element) slots per image; sums the 16 chunk
// partials for x and y in registers (coalesced), block-reduces the totals,
// then computes the Hellinger sum from the SAME registers (no hist array, no
// totals array, no memsets, no second HBM pass). One atomicAdd per block.
// ---------------------------------------------------------------------------
__global__ __launch_bounds__(1024) void finalize_kernel(
    const float* __restrict__ partial, float* __restrict__ out)
{
    const int b = blockIdx.x;              // 0..7
    const int tid = threadIdx.x;
    const int wv = tid >> 6;
    __shared__ float redx[16], redy[16];

    const float* __restrict__ px = partial + (size_t)(b * 3) * CHUNKS * 4096;
    const float* __restrict__ py = partial + (size_t)((8 + b) * 3) * CHUNKS * 4096;

    float hx[12], hy[12];
    float tx = 0.0f, ty = 0.0f;
#pragma unroll
    for (int i = 0; i < 12; ++i) {
        const int e = tid + i * 1024;      // 0..12287
        const int c = e >> 12;             // channel 0..2
        const int el = e & 4095;
        const float* __restrict__ bx = px + (size_t)c * CHUNKS * 4096 + el;
        const float* __restrict__ by = py + (size_t)c * CHUNKS * 4096 + el;
        float sx = 0.0f, sy = 0.0f;
#pragma unroll
        for (int k = 0; k < CHUNKS; ++k) {
            sx += bx[(size_t)k * 4096];
            sy += by[(size_t)k * 4096];
        }
        hx[i] = sx; hy[i] = sy;
        tx += sx; ty += sy;
    }

    // block-reduce totals, broadcast
#pragma unroll
    for (int o = 32; o > 0; o >>= 1) {
        tx += __shfl_down(tx, o, 64);
        ty += __shfl_down(ty, o, 64);
    }
    if ((tid & 63) == 0) { redx[wv] = tx; redy[wv] = ty; }
    __syncthreads();
    float TX = 0.0f, TY = 0.0f;
#pragma unroll
    for (int i = 0; i < 16; ++i) { TX += redx[i]; TY += redy[i]; }
    const float invx = 1.0f / TX, invy = 1.0f / TY;

    float h = 0.0f;
#pragma unroll
    for (int i = 0; i < 12; ++i) {
        const float d = sqrtf(hy[i] * invy) - sqrtf(hx[i] * invx);
        h = fmaf(d, d, h);
    }
#pragma unroll
    for (int o = 32; o > 0; o >>= 1) h += __shfl_down(h, o, 64);
    __syncthreads();                       // reuse redx
    if ((tid & 63) == 0) redx[wv] = h;
    __syncthreads();
    if (tid == 0) {
        float hs = 0.0f;
#pragma unroll
        for (int i = 0; i < 16; ++i) hs += redx[i];
        atomicAdd(out, sqrtf(0.5f * hs) * 0.125f);
    }
}

extern "C" void kernel_launch(void* const* d_in, const int* in_sizes, int n_in,
                              void* d_out, int out_size, void* d_ws, size_t ws_size,
                              hipStream_t stream)
{
    const float* x = (const float*)d_in[0];
    const float* y = (const float*)d_in[1];
    float* partial = (float*)d_ws;                        // 768*4096 floats (12.6 MB)
    float* outf = (float*)d_out;

    hipLaunchKernelGGL(hist_kernel, dim3(N_JOBS * CHUNKS), dim3(256), 0, stream,
                       x, y, partial, outf);
    hipLaunchKernelGGL(finalize_kernel, dim3(8), dim3(1024), 0, stream,
                       partial, outf);
}

// Round 12
// 167.220 us; speedup vs baseline: 1.4966x; 1.4966x over previous
//
#include <hip/hip_runtime.h>
#include <math.h>

#define N_PIX 65536
#define EPSF 1e-6f
#define CHUNKS 16
#define PX_PER_CHUNK 4096   // 65536 / 16
#define PX_PER_WAVE 1024    // 4 waves per block, 16 super-tiles of 64 px
#define N_TILES (PX_PER_WAVE / 64)
#define N_JOBS 48           // 2 imgs * 8 batch * 3 channels
#define N_BLOCKS (N_JOBS * CHUNKS)   // 768
#define LN2_50 34.65735903f // 50 * ln(2): log2 -> scaled-ln

typedef __attribute__((ext_vector_type(2))) float f2;
using short8 = __attribute__((ext_vector_type(8))) short;
using f32x4  = __attribute__((ext_vector_type(4))) float;

__device__ __forceinline__ float rcp_fast(float x) { return __builtin_amdgcn_rcpf(x); }

#if __has_builtin(__builtin_amdgcn_cvt_pk_bf16_f32)
typedef __attribute__((ext_vector_type(2))) __bf16 bf16x2_t;
__device__ __forceinline__ uint32_t pk_bf16(float a, float b) {
    return __builtin_bit_cast(uint32_t, __builtin_amdgcn_cvt_pk_bf16_f32(a, b));
}
#else
// fallback: round-half-up (inputs positive finite), 3 ops
__device__ __forceinline__ uint32_t pk_bf16(float a, float b) {
    const uint32_t ua = __builtin_bit_cast(uint32_t, a) + 0x8000u;
    const uint32_t ub = __builtin_bit_cast(uint32_t, b) + 0x8000u;
    return __builtin_amdgcn_perm(ub, ua, 0x07060302u);
}
#endif

// phase A: pixel -> (u*50, v*50, weight); log2-based (ln2 folded into scale)
__device__ __forceinline__ float4 phaseA(float pr, float pg, float pb, int c) {
    const float r  = pr + EPSF;
    const float g  = pg + EPSF;
    const float bl = pb + EPSF;
    const float wgt = sqrtf(fmaf(r, r, fmaf(g, g, bl * bl)));
    const float lr = __log2f(r), lg = __log2f(g), lb2 = __log2f(bl);
    // channel c: u = l_c - l_a, v = l_c - l_b;  c0:(a,b)=(g,b) c1:(r,b) c2:(r,g)
    const float l0 = (c == 0) ? lr : ((c == 1) ? lg : lb2);
    const float lu = (c == 0) ? lg : lr;
    const float lv = (c == 2) ? lg : lb2;
    return make_float4((l0 - lu) * LN2_50, (l0 - lv) * LN2_50, wgt, 0.0f);
}

// ---------------------------------------------------------------------------
// Kernel 1: per (job, chunk) partial 64x64 histogram via bf16 MFMA with
// fragment-direct operand generation. 256 thr/block x 768 blocks — R9's
// verified 105us structure, untouched: atomic-free chunked epilogue, rolled
// super-tile loop, conflict-free padded staging (SQ_LDS_BANK_CONFLICT=0),
// rcp-of-4-product, HW bf16 pack. Block 0 zeroes the 24 accumulator words
// (totals[16] + cross[8]) used by kernel 2 — replaces memset dispatches.
// (R11 note: hipLaunchCooperativeKernel silently no-ops under the harness's
// graph capture — out stayed 0. Plain dispatches only.)
// ---------------------------------------------------------------------------
__global__ __launch_bounds__(256, 4) void hist_kernel(
    const float* __restrict__ x, const float* __restrict__ y,
    float* __restrict__ partial, float* __restrict__ accum)
{
    const int blk = blockIdx.x;            // 0..767
    const int chunk = blk & (CHUNKS - 1);
    const int job = blk / CHUNKS;          // 0..47
    const int c = job % 3;
    const int ib = job / 3;                // img*8 + b
    const int img = ib >> 3;
    const int b = ib & 7;
    const float* __restrict__ src = (img == 0 ? x : y) + (size_t)b * 3 * N_PIX;

    const int tid = threadIdx.x;
    if (blk == 0 && tid < 24) accum[tid] = 0.0f;   // totals[16] + cross[8]

    __shared__ __align__(16) float lds[4096];   // 16 KB: wbufs / epilogue strips
    const int lane = tid & 63;
    const int wv = tid >> 6;
    float* __restrict__ wbuf = lds + wv * 288;  // 64 px * float4, +16B pad per 8 px

    const int quad = lane >> 4;
    const int l15 = lane & 15;
    // negated scaled centers for this lane's 4 m-rows: -(c_m * 50), m = mt*16+l15
    f2 ncb01, ncb23;
    {
        const float c0 = (-3.0f + (float)(l15)      * (6.0f / 63.0f)) * 50.0f;
        const float c1 = (-3.0f + (float)(16 + l15) * (6.0f / 63.0f)) * 50.0f;
        const float c2 = (-3.0f + (float)(32 + l15) * (6.0f / 63.0f)) * 50.0f;
        const float c3 = (-3.0f + (float)(48 + l15) * (6.0f / 63.0f)) * 50.0f;
        ncb01 = (f2){-c0, -c1};
        ncb23 = (f2){-c2, -c3};
    }
    const f2 one2 = {1.0f, 1.0f};

    f32x4 acc[16];                         // acc[mt*4+nt]
#pragma unroll
    for (int i = 0; i < 16; ++i) acc[i] = (f32x4){0.f, 0.f, 0.f, 0.f};

    const int px0 = chunk * PX_PER_CHUNK + wv * PX_PER_WAVE;

    // prefetch super-tile 0
    float pr, pg, pb;
    {
        const int n = px0 + lane;
        pr = src[n]; pg = src[N_PIX + n]; pb = src[2 * N_PIX + n];
    }

#pragma unroll 1
    for (int st = 0; st < N_TILES; ++st) {
        // ---- Phase A: one pixel per lane; stage to LDS (same-wave, in-order) ----
        const float4 uvw = phaseA(pr, pg, pb, c);
        *(float4*)(wbuf + lane * 4 + (lane >> 3) * 4) = uvw;

        if (st + 1 < N_TILES) {            // prefetch next tile's raw pixels
            const int n2 = px0 + (st + 1) * 64 + lane;
            pr = src[n2]; pg = src[N_PIX + n2]; pb = src[2 * N_PIX + n2];
        }

#pragma unroll
        for (int h = 0; h < 2; ++h) {              // two K=32 halves
            const int base = h * 32 + quad * 8;    // first pixel this lane consumes
            const float4* __restrict__ pbase =
                (const float4*)(wbuf + base * 4 + (base >> 3) * 4);
            int aU[4][4], aV[4][4];                // fragment words [mt][jp]

#pragma unroll
            for (int jp = 0; jp < 4; ++jp) {       // j = 2jp (even), 2jp+1 (odd)
                const float4 pe = pbase[2 * jp];
                const float4 po = pbase[2 * jp + 1];

                float aue[4], auo[4], bve[4], bvo[4];
#pragma unroll
                for (int eo = 0; eo < 2; ++eo) {
                    const float ru = eo ? po.x : pe.x;
                    const float rv = eo ? po.y : pe.y;
                    const float rw = eo ? po.z : pe.z;
                    float* au = eo ? auo : aue;
                    float* bv = eo ? bvo : bve;

                    const f2 ruu = {ru, ru};
                    const f2 tu01 = ruu + ncb01;
                    const f2 tu23 = ruu + ncb23;
                    const f2 qu01 = __builtin_elementwise_fma(tu01, tu01, one2);
                    const f2 qu23 = __builtin_elementwise_fma(tu23, tu23, one2);
                    // one rcp serves 4 denominators (max product ~6.5e19, fp32-safe)
                    const float pu01 = qu01.x * qu01.y;
                    const float pu23 = qu23.x * qu23.y;
                    const float Ru = rcp_fast(pu01 * pu23) * rw;   // fold w
                    const float ru01 = Ru * pu23, ru23 = Ru * pu01;
                    au[0] = ru01 * qu01.y; au[1] = ru01 * qu01.x;
                    au[2] = ru23 * qu23.y; au[3] = ru23 * qu23.x;

                    const f2 rvv = {rv, rv};
                    const f2 tv01 = rvv + ncb01;
                    const f2 tv23 = rvv + ncb23;
                    const f2 qv01 = __builtin_elementwise_fma(tv01, tv01, one2);
                    const f2 qv23 = __builtin_elementwise_fma(tv23, tv23, one2);
                    const float pv01 = qv01.x * qv01.y;
                    const float pv23 = qv23.x * qv23.y;
                    const float Rv = rcp_fast(pv01 * pv23);
                    const float rv01 = Rv * pv23, rv23 = Rv * pv01;
                    bv[0] = rv01 * qv01.y; bv[1] = rv01 * qv01.x;
                    bv[2] = rv23 * qv23.y; bv[3] = rv23 * qv23.x;
                }
#pragma unroll
                for (int mt = 0; mt < 4; ++mt) {
                    aU[mt][jp] = pk_bf16(aue[mt], auo[mt]);
                    aV[mt][jp] = pk_bf16(bve[mt], bvo[mt]);
                }
            }

            short8 af[4], bf[4];
#pragma unroll
            for (int mt = 0; mt < 4; ++mt) {
                af[mt] = __builtin_bit_cast(short8,
                    make_int4(aU[mt][0], aU[mt][1], aU[mt][2], aU[mt][3]));
                bf[mt] = __builtin_bit_cast(short8,
                    make_int4(aV[mt][0], aV[mt][1], aV[mt][2], aV[mt][3]));
            }
#pragma unroll
            for (int mt = 0; mt < 4; ++mt)
#pragma unroll
                for (int nt = 0; nt < 4; ++nt)
                    acc[mt * 4 + nt] = __builtin_amdgcn_mfma_f32_16x16x32_bf16(
                        af[mt], bf[nt], acc[mt * 4 + nt], 0, 0, 0);
        }
    }

    // ---- Atomic-free epilogue: 4 chunks over mt; linear b128 traffic only ----
    float* __restrict__ outp = partial + (size_t)blk * 4096;
#pragma unroll 1
    for (int ch = 0; ch < 4; ++ch) {
        __syncthreads();                   // previous chunk (or main loop) done
#pragma unroll
        for (int nt = 0; nt < 4; ++nt)     // wave strip: [wv][nt*256 + lane*4 + i]
            *(f32x4*)(lds + wv * 1024 + nt * 256 + lane * 4) = acc[ch * 4 + nt];
        __syncthreads();
        const int e4 = tid * 4;            // 0..1023, linear -> conflict-free b128
        const f32x4 s0 = *(const f32x4*)(lds +        e4);
        const f32x4 s1 = *(const f32x4*)(lds + 1024 + e4);
        const f32x4 s2 = *(const f32x4*)(lds + 2048 + e4);
        const f32x4 s3 = *(const f32x4*)(lds + 3072 + e4);
        const f32x4 s = (s0 + s1) + (s2 + s3);
        // e4 = nt*256 + l*4;  m = ch*16 + (l>>4)*4 + i;  n = nt*16 + (l&15)
        const int l = tid & 63;
        const int n = ((tid >> 6) << 4) | (l & 15);
        float* op = outp + (ch * 16 + (l >> 4) * 4) * 64 + n;
        op[0] = s.x; op[64] = s.y; op[128] = s.z; op[192] = s.w;
    }
}

// ---------------------------------------------------------------------------
// Kernel 2: Bhattacharyya-factored reduction. Hellinger identity:
//   sum (sqrt(y/TY)-sqrt(x/TX))^2 = 2(1 - rho), rho = sum sqrt(sx*sy)/sqrt(TX*TY)
// so no normalized-hist pass is needed. 384 blocks x 256: block (jx, sl)
// sums the 16 chunk-partials of element e for x-job jx and y-job 24+jx,
// forms sx, sy, sqrt(sx*sy); block-reduces 3 scalars; 3 atomics/block into
// accum (totals[16] + cross[8]). 1152 atomics total.
// ---------------------------------------------------------------------------
__global__ __launch_bounds__(256) void reduce_cross_kernel(
    const float* __restrict__ partial, float* __restrict__ accum)
{
    const int jx = blockIdx.x >> 4;                        // 0..23 (img0 job)
    const int bb = jx / 3;                                 // batch 0..7
    const int e = ((blockIdx.x & 15) << 8) | threadIdx.x;  // 0..4095
    const float* px = partial + (size_t)jx * CHUNKS * 4096 + e;
    const float* py = partial + (size_t)(24 + jx) * CHUNKS * 4096 + e;

    float sx = 0.0f, sy = 0.0f;
#pragma unroll
    for (int k = 0; k < CHUNKS; ++k) {
        sx += px[(size_t)k * 4096];
        sy += py[(size_t)k * 4096];
    }
    float cr = sqrtf(sx * sy);

#pragma unroll
    for (int o = 32; o > 0; o >>= 1) {
        sx += __shfl_down(sx, o, 64);
        sy += __shfl_down(sy, o, 64);
        cr += __shfl_down(cr, o, 64);
    }
    __shared__ float red[12];
    const int wv = threadIdx.x >> 6;
    if ((threadIdx.x & 63) == 0) {
        red[wv] = sx; red[4 + wv] = sy; red[8 + wv] = cr;
    }
    __syncthreads();
    if (threadIdx.x == 0) {
        atomicAdd(&accum[bb],      red[0] + red[1] + red[2] + red[3]);
        atomicAdd(&accum[8 + bb],  red[4] + red[5] + red[6] + red[7]);
        atomicAdd(&accum[16 + bb], red[8] + red[9] + red[10] + red[11]);
    }
}

// ---------------------------------------------------------------------------
// Kernel 3: out = mean_b sqrt(1 - cross_b / sqrt(TX_b * TY_b))
// ---------------------------------------------------------------------------
__global__ void final_kernel(const float* __restrict__ accum, float* __restrict__ out)
{
    if (threadIdx.x == 0) {
        float s = 0.0f;
#pragma unroll
        for (int b = 0; b < 8; ++b) {
            const float rho = accum[16 + b] * __builtin_amdgcn_rsqf(accum[b] * accum[8 + b]);
            s += sqrtf(fmaxf(1.0f - rho, 0.0f));
        }
        out[0] = s * 0.125f;
    }
}

extern "C" void kernel_launch(void* const* d_in, const int* in_sizes, int n_in,
                              void* d_out, int out_size, void* d_ws, size_t ws_size,
                              hipStream_t stream)
{
    const float* x = (const float*)d_in[0];
    const float* y = (const float*)d_in[1];
    float* ws = (float*)d_ws;
    float* partial = ws;                                  // 768*4096 floats (12.6 MB)
    float* accum = ws + (size_t)N_BLOCKS * 4096;          // 24 floats
    float* outf = (float*)d_out;

    hipLaunchKernelGGL(hist_kernel, dim3(N_BLOCKS), dim3(256), 0, stream,
                       x, y, partial, accum);
    hipLaunchKernelGGL(reduce_cross_kernel, dim3(24 * 16), dim3(256), 0, stream,
                       partial, accum);
    hipLaunchKernelGGL(final_kernel, dim3(1), dim3(64), 0, stream, accum, outf);
}